// Round 1
// baseline (4194.600 us; speedup 1.0000x reference)
//
#include <hip/hip_runtime.h>

#define NN 50000
#define EE 800000
#define FIN 128
#define HH 64
#define TT 8
#define GG 64
#define NCONVS 3
#define BN_EPS 1e-5f

__device__ __forceinline__ unsigned enc_f32(float x) {
  unsigned u = __float_as_uint(x);
  return (u & 0x80000000u) ? ~u : (u | 0x80000000u);
}
__device__ __forceinline__ float dec_f32(unsigned e) {
  unsigned u = (e & 0x80000000u) ? (e & 0x7fffffffu) : ~e;
  return __uint_as_float(u);
}

// y[N,64] = op(in[,in2]) @ W[K,64] + bias
// MODE 0: raw input; MODE 1: relu(in*scale+shift) (BN folded); MODE 2: in+in2
template <int K, int MODE>
__global__ __launch_bounds__(256) void mm_kernel(
    const float* __restrict__ in, const float* __restrict__ in2,
    const float* __restrict__ ss, const float* __restrict__ W,
    const float* __restrict__ bias, float* __restrict__ y) {
  __shared__ float Wl[K * HH];
  __shared__ float Al[16][K + 1];
  const int t = threadIdx.x;
  {
    const float4* W4 = (const float4*)W;
    float4* Wl4 = (float4*)Wl;
#pragma unroll
    for (int i = 0; i < (K * HH) / 1024; ++i) Wl4[t + i * 256] = W4[t + i * 256];
  }
  const int r = t >> 4, g = t & 15;
  const int row = blockIdx.x * 16 + r;
  if (row < NN) {
#pragma unroll
    for (int p = 0; p < K / 64; ++p) {
      const int c0 = g * 4 + p * 64;
      float4 v = *(const float4*)&in[row * K + c0];
      if (MODE == 2) {
        const float4 v2 = *(const float4*)&in2[row * K + c0];
        v.x += v2.x; v.y += v2.y; v.z += v2.z; v.w += v2.w;
      }
      if (MODE == 1) {
        v.x = fmaxf(fmaf(v.x, ss[c0 + 0], ss[64 + c0 + 0]), 0.f);
        v.y = fmaxf(fmaf(v.y, ss[c0 + 1], ss[64 + c0 + 1]), 0.f);
        v.z = fmaxf(fmaf(v.z, ss[c0 + 2], ss[64 + c0 + 2]), 0.f);
        v.w = fmaxf(fmaf(v.w, ss[c0 + 3], ss[64 + c0 + 3]), 0.f);
      }
      Al[r][c0 + 0] = v.x; Al[r][c0 + 1] = v.y;
      Al[r][c0 + 2] = v.z; Al[r][c0 + 3] = v.w;
    }
  } else {
#pragma unroll
    for (int p = 0; p < K / 64; ++p) {
      const int c0 = g * 4 + p * 64;
      Al[r][c0 + 0] = 0.f; Al[r][c0 + 1] = 0.f;
      Al[r][c0 + 2] = 0.f; Al[r][c0 + 3] = 0.f;
    }
  }
  __syncthreads();
  float ax = 0.f, ay = 0.f, az = 0.f, aw = 0.f;
#pragma unroll
  for (int k = 0; k < K; ++k) {
    const float a = Al[r][k];
    const float4 w = *(const float4*)&Wl[k * HH + g * 4];
    ax = fmaf(a, w.x, ax); ay = fmaf(a, w.y, ay);
    az = fmaf(a, w.z, az); aw = fmaf(a, w.w, aw);
  }
  if (row < NN) {
    const float4 bb = *(const float4*)&bias[g * 4];
    float4 o;
    o.x = ax + bb.x; o.y = ay + bb.y; o.z = az + bb.z; o.w = aw + bb.w;
    *(float4*)&y[row * HH + g * 4] = o;
  }
}

// per-column sum & sum-of-squares over y[N,64] -> stats[0:64]=sum, [64:128]=sumsq
__global__ __launch_bounds__(256) void stats_kernel(const float* __restrict__ y,
                                                    float* __restrict__ stats) {
  const int t = threadIdx.x;
  const int r = t >> 4, g = t & 15;
  float sx = 0, sy = 0, sz = 0, sw = 0, qx = 0, qy = 0, qz = 0, qw = 0;
  for (int row = blockIdx.x * 16 + r; row < NN; row += gridDim.x * 16) {
    const float4 v = *(const float4*)&y[row * HH + g * 4];
    sx += v.x; sy += v.y; sz += v.z; sw += v.w;
    qx = fmaf(v.x, v.x, qx); qy = fmaf(v.y, v.y, qy);
    qz = fmaf(v.z, v.z, qz); qw = fmaf(v.w, v.w, qw);
  }
#pragma unroll
  for (int off = 16; off <= 32; off <<= 1) {
    sx += __shfl_xor(sx, off); sy += __shfl_xor(sy, off);
    sz += __shfl_xor(sz, off); sw += __shfl_xor(sw, off);
    qx += __shfl_xor(qx, off); qy += __shfl_xor(qy, off);
    qz += __shfl_xor(qz, off); qw += __shfl_xor(qw, off);
  }
  __shared__ float part[4][128];
  const int wave = t >> 6, lane = t & 63;
  if (lane < 16) {
    const int c = lane * 4;
    part[wave][c + 0] = sx; part[wave][c + 1] = sy;
    part[wave][c + 2] = sz; part[wave][c + 3] = sw;
    part[wave][64 + c + 0] = qx; part[wave][64 + c + 1] = qy;
    part[wave][64 + c + 2] = qz; part[wave][64 + c + 3] = qw;
  }
  __syncthreads();
  if (t < 128)
    atomicAdd(&stats[t], part[0][t] + part[1][t] + part[2][t] + part[3][t]);
}

// stats -> scale/shift (BN train-mode, biased var); re-zero stats for next use
__global__ void finalize_kernel(float* __restrict__ stats,
                                const float* __restrict__ gamma,
                                const float* __restrict__ beta,
                                float* __restrict__ ss) {
  const int c = threadIdx.x;  // 64 threads
  const float inv = 1.f / (float)NN;
  const float mean = stats[c] * inv;
  const float var = stats[64 + c] * inv - mean * mean;
  const float sc = gamma[c] * rsqrtf(var + BN_EPS);
  ss[c] = sc;
  ss[64 + c] = fmaf(-mean, sc, beta[c]);
  stats[c] = 0.f;
  stats[64 + c] = 0.f;
}

// agg[dst] += h[src] over all edges; 16 threads per edge (float4 each)
__global__ __launch_bounds__(256) void scatter_kernel(const int* __restrict__ ei,
                                                      const float* __restrict__ h,
                                                      float* __restrict__ agg) {
  const int gid = blockIdx.x * 256 + threadIdx.x;
  const int e = gid >> 4, q = gid & 15;
  const int src = ei[e];
  const int dst = ei[EE + e];
  const float4 v = *(const float4*)&h[src * HH + q * 4];
  float* a = &agg[dst * HH + q * 4];
  atomicAdd(a + 0, v.x);
  atomicAdd(a + 1, v.y);
  atomicAdd(a + 2, v.z);
  atomicAdd(a + 3, v.w);
}

// h = relu(y2*scale+shift); r = h @ linW + linb; segment-max into outmax
__global__ __launch_bounds__(256) void bnrelu_readout_kernel(
    const float* __restrict__ y2, const float* __restrict__ ss,
    float* __restrict__ hout, const float* __restrict__ linW,
    const float* __restrict__ linb, const int* __restrict__ batch,
    unsigned* __restrict__ outmax) {
  __shared__ float Wl[HH * 9];
  const int t = threadIdx.x;
  if (t < 64) {
#pragma unroll
    for (int j = 0; j < 8; ++j) Wl[t * 9 + j] = linW[t * 8 + j];
  }
  __syncthreads();
  const int nl = t >> 3, fg = t & 7;
  const int n = blockIdx.x * 32 + nl;
  if (n >= NN) return;
  const int c0 = fg * 8;
  float hv[8];
  {
    const float4 v0 = *(const float4*)&y2[n * HH + c0];
    const float4 v1 = *(const float4*)&y2[n * HH + c0 + 4];
    hv[0] = fmaxf(fmaf(v0.x, ss[c0 + 0], ss[64 + c0 + 0]), 0.f);
    hv[1] = fmaxf(fmaf(v0.y, ss[c0 + 1], ss[64 + c0 + 1]), 0.f);
    hv[2] = fmaxf(fmaf(v0.z, ss[c0 + 2], ss[64 + c0 + 2]), 0.f);
    hv[3] = fmaxf(fmaf(v0.w, ss[c0 + 3], ss[64 + c0 + 3]), 0.f);
    hv[4] = fmaxf(fmaf(v1.x, ss[c0 + 4], ss[64 + c0 + 4]), 0.f);
    hv[5] = fmaxf(fmaf(v1.y, ss[c0 + 5], ss[64 + c0 + 5]), 0.f);
    hv[6] = fmaxf(fmaf(v1.z, ss[c0 + 6], ss[64 + c0 + 6]), 0.f);
    hv[7] = fmaxf(fmaf(v1.w, ss[c0 + 7], ss[64 + c0 + 7]), 0.f);
  }
  *(float4*)&hout[n * HH + c0] = make_float4(hv[0], hv[1], hv[2], hv[3]);
  *(float4*)&hout[n * HH + c0 + 4] = make_float4(hv[4], hv[5], hv[6], hv[7]);
  float rr[8] = {0, 0, 0, 0, 0, 0, 0, 0};
#pragma unroll
  for (int j = 0; j < 8; ++j) {
    const float a = hv[j];
    const int k = c0 + j;
#pragma unroll
    for (int u = 0; u < 8; ++u) rr[u] = fmaf(a, Wl[k * 9 + u], rr[u]);
  }
#pragma unroll
  for (int off = 1; off < 8; off <<= 1) {
#pragma unroll
    for (int u = 0; u < 8; ++u) rr[u] += __shfl_xor(rr[u], off);
  }
  if (fg == 0) {
    const int g = batch[n];
#pragma unroll
    for (int u = 0; u < 8; ++u)
      atomicMax(&outmax[g * 8 + u], enc_f32(rr[u] + linb[u]));
  }
}

__global__ void combine_kernel(const unsigned* __restrict__ outmax,
                               float* __restrict__ out) {
  const int i = blockIdx.x * 64 + threadIdx.x;  // 8 x 64 = 512
  float s = 0.f;
#pragma unroll
  for (int l = 0; l < 4; ++l) s += dec_f32(outmax[l * GG * TT + i]);
  out[i] = s;
}

extern "C" void kernel_launch(void* const* d_in, const int* in_sizes, int n_in,
                              void* d_out, int out_size, void* d_ws,
                              size_t ws_size, hipStream_t stream) {
  const float* x      = (const float*)d_in[0];
  const int*   ei     = (const int*)d_in[1];
  const int*   batch  = (const int*)d_in[2];
  const float* fh_W1  = (const float*)d_in[3];
  const float* fh_b1  = (const float*)d_in[4];
  const float* fh_g1  = (const float*)d_in[5];
  const float* fh_be1 = (const float*)d_in[6];
  const float* fh_W2  = (const float*)d_in[7];
  const float* fh_b2  = (const float*)d_in[8];
  const float* fh_g2  = (const float*)d_in[9];
  const float* fh_be2 = (const float*)d_in[10];
  const float* cv_W1  = (const float*)d_in[11];
  const float* cv_b1  = (const float*)d_in[12];
  const float* cv_g1  = (const float*)d_in[13];
  const float* cv_be1 = (const float*)d_in[14];
  const float* cv_W2  = (const float*)d_in[15];
  const float* cv_b2  = (const float*)d_in[16];
  const float* cv_g2  = (const float*)d_in[17];
  const float* cv_be2 = (const float*)d_in[18];
  const float* lin_W  = (const float*)d_in[19];
  const float* lin_b  = (const float*)d_in[20];

  float* out = (float*)d_out;          // [64,8]
  float* h = out + GG * TT;            // [N,64] final h lives in d_out; also
                                       // used as the running h buffer.

  float* y1 = (float*)d_ws;                    // [N,64]
  float* y2 = y1 + (size_t)NN * HH;            // [N,64]
  float* agg = y2;                             // aliased: agg dead before y2 written
  float* stats = y2 + (size_t)NN * HH;         // [128]
  float* ss = stats + 128;                     // [128] scale|shift
  unsigned* outmax = (unsigned*)(ss + 128);    // [4][64][8]

  hipMemsetAsync(stats, 0, 128 * sizeof(float), stream);
  hipMemsetAsync(outmax, 0, 4 * GG * TT * sizeof(unsigned), stream);

  // ---- first_h ----
  mm_kernel<FIN, 0><<<NN / 16, 256, 0, stream>>>(x, nullptr, nullptr, fh_W1, fh_b1, y1);
  stats_kernel<<<512, 256, 0, stream>>>(y1, stats);
  finalize_kernel<<<1, 64, 0, stream>>>(stats, fh_g1, fh_be1, ss);
  mm_kernel<HH, 1><<<NN / 16, 256, 0, stream>>>(y1, nullptr, ss, fh_W2, fh_b2, y2);
  stats_kernel<<<512, 256, 0, stream>>>(y2, stats);
  finalize_kernel<<<1, 64, 0, stream>>>(stats, fh_g2, fh_be2, ss);
  bnrelu_readout_kernel<<<(NN + 31) / 32, 256, 0, stream>>>(
      y2, ss, h, lin_W, lin_b, batch, outmax);

  // ---- GIN conv layers ----
  for (int l = 0; l < NCONVS; ++l) {
    hipMemsetAsync(agg, 0, (size_t)NN * HH * sizeof(float), stream);
    scatter_kernel<<<EE / 16, 256, 0, stream>>>(ei, h, agg);
    mm_kernel<HH, 2><<<NN / 16, 256, 0, stream>>>(
        h, agg, nullptr, cv_W1 + l * HH * HH, cv_b1 + l * HH, y1);
    stats_kernel<<<512, 256, 0, stream>>>(y1, stats);
    finalize_kernel<<<1, 64, 0, stream>>>(stats, cv_g1 + l * HH, cv_be1 + l * HH, ss);
    mm_kernel<HH, 1><<<NN / 16, 256, 0, stream>>>(
        y1, nullptr, ss, cv_W2 + l * HH * HH, cv_b2 + l * HH, y2);
    stats_kernel<<<512, 256, 0, stream>>>(y2, stats);
    finalize_kernel<<<1, 64, 0, stream>>>(stats, cv_g2 + l * HH, cv_be2 + l * HH, ss);
    bnrelu_readout_kernel<<<(NN + 31) / 32, 256, 0, stream>>>(
        y2, ss, h, lin_W + (l + 1) * HH * TT, lin_b + (l + 1) * TT, batch,
        outmax + (l + 1) * GG * TT);
  }
  combine_kernel<<<8, 64, 0, stream>>>(outmax, out);
}

// Round 2
// 2390.908 us; speedup vs baseline: 1.7544x; 1.7544x over previous
//
#include <hip/hip_runtime.h>

#define NN 50000
#define EE 800000
#define FIN 128
#define HH 64
#define TT 8
#define GG 64
#define NCONVS 3
#define BN_EPS 1e-5f
#define NB_SCAN 196  // ceil(NN/256)

__device__ __forceinline__ unsigned enc_f32(float x) {
  unsigned u = __float_as_uint(x);
  return (u & 0x80000000u) ? ~u : (u | 0x80000000u);
}
__device__ __forceinline__ float dec_f32(unsigned e) {
  unsigned u = (e & 0x80000000u) ? (e & 0x7fffffffu) : ~e;
  return __uint_as_float(u);
}

// y[N,64] = op(in[,in2]) @ W[K,64] + bias
// MODE 0: raw input; MODE 1: relu(in*scale+shift) (BN folded); MODE 2: in+in2
template <int K, int MODE>
__global__ __launch_bounds__(256) void mm_kernel(
    const float* __restrict__ in, const float* __restrict__ in2,
    const float* __restrict__ ss, const float* __restrict__ W,
    const float* __restrict__ bias, float* __restrict__ y) {
  __shared__ float Wl[K * HH];
  __shared__ float Al[16][K + 1];
  const int t = threadIdx.x;
  {
    const float4* W4 = (const float4*)W;
    float4* Wl4 = (float4*)Wl;
#pragma unroll
    for (int i = 0; i < (K * HH) / 1024; ++i) Wl4[t + i * 256] = W4[t + i * 256];
  }
  const int r = t >> 4, g = t & 15;
  const int row = blockIdx.x * 16 + r;
  if (row < NN) {
#pragma unroll
    for (int p = 0; p < K / 64; ++p) {
      const int c0 = g * 4 + p * 64;
      float4 v = *(const float4*)&in[row * K + c0];
      if (MODE == 2) {
        const float4 v2 = *(const float4*)&in2[row * K + c0];
        v.x += v2.x; v.y += v2.y; v.z += v2.z; v.w += v2.w;
      }
      if (MODE == 1) {
        v.x = fmaxf(fmaf(v.x, ss[c0 + 0], ss[64 + c0 + 0]), 0.f);
        v.y = fmaxf(fmaf(v.y, ss[c0 + 1], ss[64 + c0 + 1]), 0.f);
        v.z = fmaxf(fmaf(v.z, ss[c0 + 2], ss[64 + c0 + 2]), 0.f);
        v.w = fmaxf(fmaf(v.w, ss[c0 + 3], ss[64 + c0 + 3]), 0.f);
      }
      Al[r][c0 + 0] = v.x; Al[r][c0 + 1] = v.y;
      Al[r][c0 + 2] = v.z; Al[r][c0 + 3] = v.w;
    }
  } else {
#pragma unroll
    for (int p = 0; p < K / 64; ++p) {
      const int c0 = g * 4 + p * 64;
      Al[r][c0 + 0] = 0.f; Al[r][c0 + 1] = 0.f;
      Al[r][c0 + 2] = 0.f; Al[r][c0 + 3] = 0.f;
    }
  }
  __syncthreads();
  float ax = 0.f, ay = 0.f, az = 0.f, aw = 0.f;
#pragma unroll
  for (int k = 0; k < K; ++k) {
    const float a = Al[r][k];
    const float4 w = *(const float4*)&Wl[k * HH + g * 4];
    ax = fmaf(a, w.x, ax); ay = fmaf(a, w.y, ay);
    az = fmaf(a, w.z, az); aw = fmaf(a, w.w, aw);
  }
  if (row < NN) {
    const float4 bb = *(const float4*)&bias[g * 4];
    float4 o;
    o.x = ax + bb.x; o.y = ay + bb.y; o.z = az + bb.z; o.w = aw + bb.w;
    *(float4*)&y[row * HH + g * 4] = o;
  }
}

// per-column sum & sum-of-squares over y[N,64] -> stats[0:64]=sum, [64:128]=sumsq
__global__ __launch_bounds__(256) void stats_kernel(const float* __restrict__ y,
                                                    float* __restrict__ stats) {
  const int t = threadIdx.x;
  const int r = t >> 4, g = t & 15;
  float sx = 0, sy = 0, sz = 0, sw = 0, qx = 0, qy = 0, qz = 0, qw = 0;
  for (int row = blockIdx.x * 16 + r; row < NN; row += gridDim.x * 16) {
    const float4 v = *(const float4*)&y[row * HH + g * 4];
    sx += v.x; sy += v.y; sz += v.z; sw += v.w;
    qx = fmaf(v.x, v.x, qx); qy = fmaf(v.y, v.y, qy);
    qz = fmaf(v.z, v.z, qz); qw = fmaf(v.w, v.w, qw);
  }
#pragma unroll
  for (int off = 16; off <= 32; off <<= 1) {
    sx += __shfl_xor(sx, off); sy += __shfl_xor(sy, off);
    sz += __shfl_xor(sz, off); sw += __shfl_xor(sw, off);
    qx += __shfl_xor(qx, off); qy += __shfl_xor(qy, off);
    qz += __shfl_xor(qz, off); qw += __shfl_xor(qw, off);
  }
  __shared__ float part[4][128];
  const int wave = t >> 6, lane = t & 63;
  if (lane < 16) {
    const int c = lane * 4;
    part[wave][c + 0] = sx; part[wave][c + 1] = sy;
    part[wave][c + 2] = sz; part[wave][c + 3] = sw;
    part[wave][64 + c + 0] = qx; part[wave][64 + c + 1] = qy;
    part[wave][64 + c + 2] = qz; part[wave][64 + c + 3] = qw;
  }
  __syncthreads();
  if (t < 128)
    atomicAdd(&stats[t], part[0][t] + part[1][t] + part[2][t] + part[3][t]);
}

// stats -> scale/shift (BN train-mode, biased var); re-zero stats for next use
__global__ void finalize_kernel(float* __restrict__ stats,
                                const float* __restrict__ gamma,
                                const float* __restrict__ beta,
                                float* __restrict__ ss) {
  const int c = threadIdx.x;  // 64 threads
  const float inv = 1.f / (float)NN;
  const float mean = stats[c] * inv;
  const float var = stats[64 + c] * inv - mean * mean;
  const float sc = gamma[c] * rsqrtf(var + BN_EPS);
  ss[c] = sc;
  ss[64 + c] = fmaf(-mean, sc, beta[c]);
  stats[c] = 0.f;
  stats[64 + c] = 0.f;
}

// ---------------- CSR build ----------------
__global__ __launch_bounds__(256) void hist_kernel(const int* __restrict__ ei,
                                                   int* __restrict__ deg) {
  const int e = blockIdx.x * 256 + threadIdx.x;
  if (e < EE) atomicAdd(&deg[ei[EE + e]], 1);
}

__global__ __launch_bounds__(256) void scan1_kernel(const int* __restrict__ deg,
                                                    int* __restrict__ bsum) {
  __shared__ int s[256];
  const int i = blockIdx.x * 256 + threadIdx.x;
  s[threadIdx.x] = (i < NN) ? deg[i] : 0;
  __syncthreads();
  for (int off = 128; off > 0; off >>= 1) {
    if (threadIdx.x < off) s[threadIdx.x] += s[threadIdx.x + off];
    __syncthreads();
  }
  if (threadIdx.x == 0) bsum[blockIdx.x] = s[0];
}

// single block: exclusive scan of NB_SCAN block sums (in place)
__global__ void scan2_kernel(int* __restrict__ bsum) {
  __shared__ int s[256];
  const int t = threadIdx.x;
  const int orig = (t < NB_SCAN) ? bsum[t] : 0;
  s[t] = orig;
  __syncthreads();
  for (int off = 1; off < 256; off <<= 1) {
    const int u = (t >= off) ? s[t - off] : 0;
    __syncthreads();
    s[t] += u;
    __syncthreads();
  }
  if (t < NB_SCAN) bsum[t] = s[t] - orig;  // exclusive
}

__global__ __launch_bounds__(256) void scan3_kernel(const int* __restrict__ deg,
                                                    const int* __restrict__ bsum,
                                                    int* __restrict__ offs,
                                                    int* __restrict__ cursor) {
  __shared__ int s[256];
  const int t = threadIdx.x;
  const int i = blockIdx.x * 256 + t;
  const int orig = (i < NN) ? deg[i] : 0;
  s[t] = orig;
  __syncthreads();
  for (int off = 1; off < 256; off <<= 1) {
    const int u = (t >= off) ? s[t - off] : 0;
    __syncthreads();
    s[t] += u;
    __syncthreads();
  }
  const int excl = s[t] - orig + bsum[blockIdx.x];
  if (i < NN) {
    offs[i] = excl;
    cursor[i] = excl;
    if (i == NN - 1) offs[NN] = excl + orig;
  }
}

__global__ __launch_bounds__(256) void fill_kernel(const int* __restrict__ ei,
                                                   int* __restrict__ cursor,
                                                   int* __restrict__ srcs) {
  const int e = blockIdx.x * 256 + threadIdx.x;
  if (e < EE) {
    const int dst = ei[EE + e];
    const int pos = atomicAdd(&cursor[dst], 1);
    srcs[pos] = ei[e];
  }
}

// agg[n] = sum over CSR neighbors of h[src]; 16 lanes per node, no atomics
__global__ __launch_bounds__(256) void gather_kernel(const int* __restrict__ offs,
                                                     const int* __restrict__ srcs,
                                                     const float* __restrict__ h,
                                                     float* __restrict__ agg) {
  const int gid = blockIdx.x * 256 + threadIdx.x;
  const int n = gid >> 4, q = gid & 15;
  if (n >= NN) return;
  const int s0 = offs[n], s1 = offs[n + 1];
  float4 acc = make_float4(0.f, 0.f, 0.f, 0.f);
  for (int j = s0; j < s1; ++j) {
    const int src = srcs[j];
    const float4 v = *(const float4*)&h[src * HH + q * 4];
    acc.x += v.x; acc.y += v.y; acc.z += v.z; acc.w += v.w;
  }
  *(float4*)&agg[n * HH + q * 4] = acc;
}

// fallback (atomic) aggregation, used only if ws too small for CSR
__global__ __launch_bounds__(256) void scatter_kernel(const int* __restrict__ ei,
                                                      const float* __restrict__ h,
                                                      float* __restrict__ agg) {
  const int gid = blockIdx.x * 256 + threadIdx.x;
  const int e = gid >> 4, q = gid & 15;
  const int src = ei[e];
  const int dst = ei[EE + e];
  const float4 v = *(const float4*)&h[src * HH + q * 4];
  float* a = &agg[dst * HH + q * 4];
  atomicAdd(a + 0, v.x);
  atomicAdd(a + 1, v.y);
  atomicAdd(a + 2, v.z);
  atomicAdd(a + 3, v.w);
}

// h = relu(y2*scale+shift); r = h @ linW + linb; segment-max into outmax
__global__ __launch_bounds__(256) void bnrelu_readout_kernel(
    const float* __restrict__ y2, const float* __restrict__ ss,
    float* __restrict__ hout, const float* __restrict__ linW,
    const float* __restrict__ linb, const int* __restrict__ batch,
    unsigned* __restrict__ outmax) {
  __shared__ float Wl[HH * 9];
  const int t = threadIdx.x;
  if (t < 64) {
#pragma unroll
    for (int j = 0; j < 8; ++j) Wl[t * 9 + j] = linW[t * 8 + j];
  }
  __syncthreads();
  const int nl = t >> 3, fg = t & 7;
  const int n = blockIdx.x * 32 + nl;
  if (n >= NN) return;
  const int c0 = fg * 8;
  float hv[8];
  {
    const float4 v0 = *(const float4*)&y2[n * HH + c0];
    const float4 v1 = *(const float4*)&y2[n * HH + c0 + 4];
    hv[0] = fmaxf(fmaf(v0.x, ss[c0 + 0], ss[64 + c0 + 0]), 0.f);
    hv[1] = fmaxf(fmaf(v0.y, ss[c0 + 1], ss[64 + c0 + 1]), 0.f);
    hv[2] = fmaxf(fmaf(v0.z, ss[c0 + 2], ss[64 + c0 + 2]), 0.f);
    hv[3] = fmaxf(fmaf(v0.w, ss[c0 + 3], ss[64 + c0 + 3]), 0.f);
    hv[4] = fmaxf(fmaf(v1.x, ss[c0 + 4], ss[64 + c0 + 4]), 0.f);
    hv[5] = fmaxf(fmaf(v1.y, ss[c0 + 5], ss[64 + c0 + 5]), 0.f);
    hv[6] = fmaxf(fmaf(v1.z, ss[c0 + 6], ss[64 + c0 + 6]), 0.f);
    hv[7] = fmaxf(fmaf(v1.w, ss[c0 + 7], ss[64 + c0 + 7]), 0.f);
  }
  *(float4*)&hout[n * HH + c0] = make_float4(hv[0], hv[1], hv[2], hv[3]);
  *(float4*)&hout[n * HH + c0 + 4] = make_float4(hv[4], hv[5], hv[6], hv[7]);
  float rr[8] = {0, 0, 0, 0, 0, 0, 0, 0};
#pragma unroll
  for (int j = 0; j < 8; ++j) {
    const float a = hv[j];
    const int k = c0 + j;
#pragma unroll
    for (int u = 0; u < 8; ++u) rr[u] = fmaf(a, Wl[k * 9 + u], rr[u]);
  }
#pragma unroll
  for (int off = 1; off < 8; off <<= 1) {
#pragma unroll
    for (int u = 0; u < 8; ++u) rr[u] += __shfl_xor(rr[u], off);
  }
  if (fg == 0) {
    const int g = batch[n];
#pragma unroll
    for (int u = 0; u < 8; ++u)
      atomicMax(&outmax[g * 8 + u], enc_f32(rr[u] + linb[u]));
  }
}

__global__ void combine_kernel(const unsigned* __restrict__ outmax,
                               float* __restrict__ out) {
  const int i = blockIdx.x * 64 + threadIdx.x;  // 8 x 64 = 512
  float s = 0.f;
#pragma unroll
  for (int l = 0; l < 4; ++l) s += dec_f32(outmax[l * GG * TT + i]);
  out[i] = s;
}

extern "C" void kernel_launch(void* const* d_in, const int* in_sizes, int n_in,
                              void* d_out, int out_size, void* d_ws,
                              size_t ws_size, hipStream_t stream) {
  const float* x      = (const float*)d_in[0];
  const int*   ei     = (const int*)d_in[1];
  const int*   batch  = (const int*)d_in[2];
  const float* fh_W1  = (const float*)d_in[3];
  const float* fh_b1  = (const float*)d_in[4];
  const float* fh_g1  = (const float*)d_in[5];
  const float* fh_be1 = (const float*)d_in[6];
  const float* fh_W2  = (const float*)d_in[7];
  const float* fh_b2  = (const float*)d_in[8];
  const float* fh_g2  = (const float*)d_in[9];
  const float* fh_be2 = (const float*)d_in[10];
  const float* cv_W1  = (const float*)d_in[11];
  const float* cv_b1  = (const float*)d_in[12];
  const float* cv_g1  = (const float*)d_in[13];
  const float* cv_be1 = (const float*)d_in[14];
  const float* cv_W2  = (const float*)d_in[15];
  const float* cv_b2  = (const float*)d_in[16];
  const float* cv_g2  = (const float*)d_in[17];
  const float* cv_be2 = (const float*)d_in[18];
  const float* lin_W  = (const float*)d_in[19];
  const float* lin_b  = (const float*)d_in[20];

  float* out = (float*)d_out;  // [64,8]
  float* h = out + GG * TT;    // [N,64] final h lives in d_out; running h buf.

  // ---- workspace layout ----
  // persistent small: stats[128] ss[128] outmax[2048] bsum[256]
  // CSR (persistent within call): offs[NN+1], srcs[EE]
  // big: y1[NN*HH], y2[NN*HH]  (deg/cursor alias y1 during build)
  char* w = (char*)d_ws;
  float* stats = (float*)w;                       w += 128 * 4;
  float* ss = (float*)w;                          w += 128 * 4;
  unsigned* outmax = (unsigned*)w;                w += 4 * GG * TT * 4;
  int* bsum = (int*)w;                            w += 256 * 4;
  int* offs = (int*)w;                            w += (NN + 1) * 4;
  int* srcs = (int*)w;                            w += (size_t)EE * 4;
  // align to 16
  w = (char*)(((size_t)w + 15) & ~(size_t)15);
  float* y1 = (float*)w;                          w += (size_t)NN * HH * 4;
  float* y2 = (float*)w;                          w += (size_t)NN * HH * 4;
  const size_t need_csr = (size_t)(w - (char*)d_ws);
  const bool use_csr = ws_size >= need_csr;
  float* agg = y2;  // aliased: agg dead before y2 written
  int* deg = (int*)y1;         // build-time aliases (dead before y1 written)
  int* cursor = ((int*)y1) + NN;

  hipMemsetAsync(stats, 0, 128 * sizeof(float), stream);
  hipMemsetAsync(outmax, 0, 4 * GG * TT * sizeof(unsigned), stream);

  if (use_csr) {
    hipMemsetAsync(deg, 0, NN * sizeof(int), stream);
    hist_kernel<<<(EE + 255) / 256, 256, 0, stream>>>(ei, deg);
    scan1_kernel<<<NB_SCAN, 256, 0, stream>>>(deg, bsum);
    scan2_kernel<<<1, 256, 0, stream>>>(bsum);
    scan3_kernel<<<NB_SCAN, 256, 0, stream>>>(deg, bsum, offs, cursor);
    fill_kernel<<<(EE + 255) / 256, 256, 0, stream>>>(ei, cursor, srcs);
  }

  // ---- first_h ----
  mm_kernel<FIN, 0><<<NN / 16, 256, 0, stream>>>(x, nullptr, nullptr, fh_W1, fh_b1, y1);
  stats_kernel<<<512, 256, 0, stream>>>(y1, stats);
  finalize_kernel<<<1, 64, 0, stream>>>(stats, fh_g1, fh_be1, ss);
  mm_kernel<HH, 1><<<NN / 16, 256, 0, stream>>>(y1, nullptr, ss, fh_W2, fh_b2, y2);
  stats_kernel<<<512, 256, 0, stream>>>(y2, stats);
  finalize_kernel<<<1, 64, 0, stream>>>(stats, fh_g2, fh_be2, ss);
  bnrelu_readout_kernel<<<(NN + 31) / 32, 256, 0, stream>>>(
      y2, ss, h, lin_W, lin_b, batch, outmax);

  // ---- GIN conv layers ----
  for (int l = 0; l < NCONVS; ++l) {
    if (use_csr) {
      gather_kernel<<<(NN * 16) / 256, 256, 0, stream>>>(offs, srcs, h, agg);
    } else {
      hipMemsetAsync(agg, 0, (size_t)NN * HH * sizeof(float), stream);
      scatter_kernel<<<EE / 16, 256, 0, stream>>>(ei, h, agg);
    }
    mm_kernel<HH, 2><<<NN / 16, 256, 0, stream>>>(
        h, agg, nullptr, cv_W1 + l * HH * HH, cv_b1 + l * HH, y1);
    stats_kernel<<<512, 256, 0, stream>>>(y1, stats);
    finalize_kernel<<<1, 64, 0, stream>>>(stats, cv_g1 + l * HH, cv_be1 + l * HH, ss);
    mm_kernel<HH, 1><<<NN / 16, 256, 0, stream>>>(
        y1, nullptr, ss, cv_W2 + l * HH * HH, cv_b2 + l * HH, y2);
    stats_kernel<<<512, 256, 0, stream>>>(y2, stats);
    finalize_kernel<<<1, 64, 0, stream>>>(stats, cv_g2 + l * HH, cv_be2 + l * HH, ss);
    bnrelu_readout_kernel<<<(NN + 31) / 32, 256, 0, stream>>>(
        y2, ss, h, lin_W + (l + 1) * HH * TT, lin_b + (l + 1) * TT, batch,
        outmax + (l + 1) * GG * TT);
  }
  combine_kernel<<<8, 64, 0, stream>>>(outmax, out);
}

// Round 3
// 463.235 us; speedup vs baseline: 9.0550x; 5.1613x over previous
//
#include <hip/hip_runtime.h>

#define NN 50000
#define EE 800000
#define FIN 128
#define HH 64
#define TT 8
#define GG 64
#define NCONVS 3
#define BN_EPS 1e-5f
#define NB_SCAN 196   // ceil(NN/256)
#define RNODES 128    // nodes per readout block

__device__ __forceinline__ unsigned enc_f32(float x) {
  unsigned u = __float_as_uint(x);
  return (u & 0x80000000u) ? ~u : (u | 0x80000000u);
}
__device__ __forceinline__ float dec_f32(unsigned e) {
  unsigned u = (e & 0x80000000u) ? (e & 0x7fffffffu) : ~e;
  return __uint_as_float(u);
}

// y[N,64] = op(in[,in2]) @ W[K,64] + bias
// MODE 0: raw input; MODE 1: relu(in*scale+shift) (BN folded); MODE 2: in+in2
template <int K, int MODE>
__global__ __launch_bounds__(256) void mm_kernel(
    const float* __restrict__ in, const float* __restrict__ in2,
    const float* __restrict__ ss, const float* __restrict__ W,
    const float* __restrict__ bias, float* __restrict__ y) {
  __shared__ float Wl[K * HH];
  __shared__ float Al[16][K + 1];
  const int t = threadIdx.x;
  {
    const float4* W4 = (const float4*)W;
    float4* Wl4 = (float4*)Wl;
#pragma unroll
    for (int i = 0; i < (K * HH) / 1024; ++i) Wl4[t + i * 256] = W4[t + i * 256];
  }
  const int r = t >> 4, g = t & 15;
  const int row = blockIdx.x * 16 + r;
  if (row < NN) {
#pragma unroll
    for (int p = 0; p < K / 64; ++p) {
      const int c0 = g * 4 + p * 64;
      float4 v = *(const float4*)&in[row * K + c0];
      if (MODE == 2) {
        const float4 v2 = *(const float4*)&in2[row * K + c0];
        v.x += v2.x; v.y += v2.y; v.z += v2.z; v.w += v2.w;
      }
      if (MODE == 1) {
        v.x = fmaxf(fmaf(v.x, ss[c0 + 0], ss[64 + c0 + 0]), 0.f);
        v.y = fmaxf(fmaf(v.y, ss[c0 + 1], ss[64 + c0 + 1]), 0.f);
        v.z = fmaxf(fmaf(v.z, ss[c0 + 2], ss[64 + c0 + 2]), 0.f);
        v.w = fmaxf(fmaf(v.w, ss[c0 + 3], ss[64 + c0 + 3]), 0.f);
      }
      Al[r][c0 + 0] = v.x; Al[r][c0 + 1] = v.y;
      Al[r][c0 + 2] = v.z; Al[r][c0 + 3] = v.w;
    }
  } else {
#pragma unroll
    for (int p = 0; p < K / 64; ++p) {
      const int c0 = g * 4 + p * 64;
      Al[r][c0 + 0] = 0.f; Al[r][c0 + 1] = 0.f;
      Al[r][c0 + 2] = 0.f; Al[r][c0 + 3] = 0.f;
    }
  }
  __syncthreads();
  float ax = 0.f, ay = 0.f, az = 0.f, aw = 0.f;
#pragma unroll
  for (int k = 0; k < K; ++k) {
    const float a = Al[r][k];
    const float4 w = *(const float4*)&Wl[k * HH + g * 4];
    ax = fmaf(a, w.x, ax); ay = fmaf(a, w.y, ay);
    az = fmaf(a, w.z, az); aw = fmaf(a, w.w, aw);
  }
  if (row < NN) {
    const float4 bb = *(const float4*)&bias[g * 4];
    float4 o;
    o.x = ax + bb.x; o.y = ay + bb.y; o.z = az + bb.z; o.w = aw + bb.w;
    *(float4*)&y[row * HH + g * 4] = o;
  }
}

// per-column sum & sum-of-squares over y[N,64] -> stats[0:64]=sum, [64:128]=sumsq
__global__ __launch_bounds__(256) void stats_kernel(const float* __restrict__ y,
                                                    float* __restrict__ stats) {
  const int t = threadIdx.x;
  const int r = t >> 4, g = t & 15;
  float sx = 0, sy = 0, sz = 0, sw = 0, qx = 0, qy = 0, qz = 0, qw = 0;
  for (int row = blockIdx.x * 16 + r; row < NN; row += gridDim.x * 16) {
    const float4 v = *(const float4*)&y[row * HH + g * 4];
    sx += v.x; sy += v.y; sz += v.z; sw += v.w;
    qx = fmaf(v.x, v.x, qx); qy = fmaf(v.y, v.y, qy);
    qz = fmaf(v.z, v.z, qz); qw = fmaf(v.w, v.w, qw);
  }
#pragma unroll
  for (int off = 16; off <= 32; off <<= 1) {
    sx += __shfl_xor(sx, off); sy += __shfl_xor(sy, off);
    sz += __shfl_xor(sz, off); sw += __shfl_xor(sw, off);
    qx += __shfl_xor(qx, off); qy += __shfl_xor(qy, off);
    qz += __shfl_xor(qz, off); qw += __shfl_xor(qw, off);
  }
  __shared__ float part[4][128];
  const int wave = t >> 6, lane = t & 63;
  if (lane < 16) {
    const int c = lane * 4;
    part[wave][c + 0] = sx; part[wave][c + 1] = sy;
    part[wave][c + 2] = sz; part[wave][c + 3] = sw;
    part[wave][64 + c + 0] = qx; part[wave][64 + c + 1] = qy;
    part[wave][64 + c + 2] = qz; part[wave][64 + c + 3] = qw;
  }
  __syncthreads();
  if (t < 128)
    atomicAdd(&stats[t], part[0][t] + part[1][t] + part[2][t] + part[3][t]);
}

// stats -> scale/shift (BN train-mode, biased var); re-zero stats for next use
__global__ void finalize_kernel(float* __restrict__ stats,
                                const float* __restrict__ gamma,
                                const float* __restrict__ beta,
                                float* __restrict__ ss) {
  const int c = threadIdx.x;  // 64 threads
  const float inv = 1.f / (float)NN;
  const float mean = stats[c] * inv;
  const float var = stats[64 + c] * inv - mean * mean;
  const float sc = gamma[c] * rsqrtf(var + BN_EPS);
  ss[c] = sc;
  ss[64 + c] = fmaf(-mean, sc, beta[c]);
  stats[c] = 0.f;
  stats[64 + c] = 0.f;
}

// ---------------- CSR build ----------------
__global__ __launch_bounds__(256) void hist_kernel(const int* __restrict__ ei,
                                                   int* __restrict__ deg) {
  const int e = blockIdx.x * 256 + threadIdx.x;
  if (e < EE) atomicAdd(&deg[ei[EE + e]], 1);
}

__global__ __launch_bounds__(256) void scan1_kernel(const int* __restrict__ deg,
                                                    int* __restrict__ bsum) {
  __shared__ int s[256];
  const int i = blockIdx.x * 256 + threadIdx.x;
  s[threadIdx.x] = (i < NN) ? deg[i] : 0;
  __syncthreads();
  for (int off = 128; off > 0; off >>= 1) {
    if (threadIdx.x < off) s[threadIdx.x] += s[threadIdx.x + off];
    __syncthreads();
  }
  if (threadIdx.x == 0) bsum[blockIdx.x] = s[0];
}

// single block: exclusive scan of NB_SCAN block sums (in place)
__global__ void scan2_kernel(int* __restrict__ bsum) {
  __shared__ int s[256];
  const int t = threadIdx.x;
  const int orig = (t < NB_SCAN) ? bsum[t] : 0;
  s[t] = orig;
  __syncthreads();
  for (int off = 1; off < 256; off <<= 1) {
    const int u = (t >= off) ? s[t - off] : 0;
    __syncthreads();
    s[t] += u;
    __syncthreads();
  }
  if (t < NB_SCAN) bsum[t] = s[t] - orig;  // exclusive
}

__global__ __launch_bounds__(256) void scan3_kernel(const int* __restrict__ deg,
                                                    const int* __restrict__ bsum,
                                                    int* __restrict__ offs,
                                                    int* __restrict__ cursor) {
  __shared__ int s[256];
  const int t = threadIdx.x;
  const int i = blockIdx.x * 256 + t;
  const int orig = (i < NN) ? deg[i] : 0;
  s[t] = orig;
  __syncthreads();
  for (int off = 1; off < 256; off <<= 1) {
    const int u = (t >= off) ? s[t - off] : 0;
    __syncthreads();
    s[t] += u;
    __syncthreads();
  }
  const int excl = s[t] - orig + bsum[blockIdx.x];
  if (i < NN) {
    offs[i] = excl;
    cursor[i] = excl;
    if (i == NN - 1) offs[NN] = excl + orig;
  }
}

__global__ __launch_bounds__(256) void fill_kernel(const int* __restrict__ ei,
                                                   int* __restrict__ cursor,
                                                   int* __restrict__ srcs) {
  const int e = blockIdx.x * 256 + threadIdx.x;
  if (e < EE) {
    const int dst = ei[EE + e];
    const int pos = atomicAdd(&cursor[dst], 1);
    srcs[pos] = ei[e];
  }
}

// agg[n] = sum over CSR neighbors of h[src]; 16 lanes per node, no atomics
__global__ __launch_bounds__(256) void gather_kernel(const int* __restrict__ offs,
                                                     const int* __restrict__ srcs,
                                                     const float* __restrict__ h,
                                                     float* __restrict__ agg) {
  const int gid = blockIdx.x * 256 + threadIdx.x;
  const int n = gid >> 4, q = gid & 15;
  if (n >= NN) return;
  const int s0 = offs[n], s1 = offs[n + 1];
  float4 acc = make_float4(0.f, 0.f, 0.f, 0.f);
  for (int j = s0; j < s1; ++j) {
    const int src = srcs[j];
    const float4 v = *(const float4*)&h[src * HH + q * 4];
    acc.x += v.x; acc.y += v.y; acc.z += v.z; acc.w += v.w;
  }
  *(float4*)&agg[n * HH + q * 4] = acc;
}

// fallback (atomic) aggregation, used only if ws too small for CSR
__global__ __launch_bounds__(256) void scatter_kernel(const int* __restrict__ ei,
                                                      const float* __restrict__ h,
                                                      float* __restrict__ agg) {
  const int gid = blockIdx.x * 256 + threadIdx.x;
  const int e = gid >> 4, q = gid & 15;
  const int src = ei[e];
  const int dst = ei[EE + e];
  const float4 v = *(const float4*)&h[src * HH + q * 4];
  float* a = &agg[dst * HH + q * 4];
  atomicAdd(a + 0, v.x);
  atomicAdd(a + 1, v.y);
  atomicAdd(a + 2, v.z);
  atomicAdd(a + 3, v.w);
}

// h = relu(y2*scale+shift); r = h @ linW + linb; segment-max via LDS staging.
// Block owns RNODES consecutive nodes (batch sorted -> few distinct groups).
__global__ __launch_bounds__(256) void bnrelu_readout_kernel(
    const float* __restrict__ y2, const float* __restrict__ ss,
    float* __restrict__ hout, const float* __restrict__ linW,
    const float* __restrict__ linb, const int* __restrict__ batch,
    unsigned* __restrict__ outmax) {
  __shared__ float Wl[HH * 9];
  __shared__ float lb[8];
  __shared__ unsigned smax[8][8];
  const int t = threadIdx.x;
  if (t < 64) {
#pragma unroll
    for (int j = 0; j < 8; ++j) Wl[t * 9 + j] = linW[t * 8 + j];
  }
  if (t < 8) lb[t] = linb[t];
  if (t >= 64 && t < 128) smax[(t - 64) >> 3][(t - 64) & 7] = 0u;
  const int gfirst = batch[blockIdx.x * RNODES < NN ? blockIdx.x * RNODES : NN - 1];
  __syncthreads();
  const int nl = t >> 3, fg = t & 3 | (t & 7);  // fg = t & 7
  const int c0 = (t & 7) * 8;
  const int b0 = t & 1, b1 = (t >> 1) & 1, b2 = (t >> 2) & 1;
#pragma unroll
  for (int chunk = 0; chunk < RNODES / 32; ++chunk) {
    const int n = blockIdx.x * RNODES + chunk * 32 + nl;
    if (n < NN) {
      float hv[8];
      {
        const float4 v0 = *(const float4*)&y2[n * HH + c0];
        const float4 v1 = *(const float4*)&y2[n * HH + c0 + 4];
        hv[0] = fmaxf(fmaf(v0.x, ss[c0 + 0], ss[64 + c0 + 0]), 0.f);
        hv[1] = fmaxf(fmaf(v0.y, ss[c0 + 1], ss[64 + c0 + 1]), 0.f);
        hv[2] = fmaxf(fmaf(v0.z, ss[c0 + 2], ss[64 + c0 + 2]), 0.f);
        hv[3] = fmaxf(fmaf(v0.w, ss[c0 + 3], ss[64 + c0 + 3]), 0.f);
        hv[4] = fmaxf(fmaf(v1.x, ss[c0 + 4], ss[64 + c0 + 4]), 0.f);
        hv[5] = fmaxf(fmaf(v1.y, ss[c0 + 5], ss[64 + c0 + 5]), 0.f);
        hv[6] = fmaxf(fmaf(v1.z, ss[c0 + 6], ss[64 + c0 + 6]), 0.f);
        hv[7] = fmaxf(fmaf(v1.w, ss[c0 + 7], ss[64 + c0 + 7]), 0.f);
      }
      *(float4*)&hout[n * HH + c0] = make_float4(hv[0], hv[1], hv[2], hv[3]);
      *(float4*)&hout[n * HH + c0 + 4] = make_float4(hv[4], hv[5], hv[6], hv[7]);
      float rr[8] = {0, 0, 0, 0, 0, 0, 0, 0};
#pragma unroll
      for (int j = 0; j < 8; ++j) {
        const float a = hv[j];
        const int k = c0 + j;
#pragma unroll
        for (int u = 0; u < 8; ++u) rr[u] = fmaf(a, Wl[k * 9 + u], rr[u]);
      }
      // reduce-scatter butterfly: lane (t&7) ends with full sum for u == t&7
      float s4[4];
#pragma unroll
      for (int i = 0; i < 4; ++i) {
        const float keepv = b0 ? rr[2 * i + 1] : rr[2 * i];
        const float send = b0 ? rr[2 * i] : rr[2 * i + 1];
        s4[i] = keepv + __shfl_xor(send, 1);
      }
      float s2[2];
#pragma unroll
      for (int i = 0; i < 2; ++i) {
        const float keepv = b1 ? s4[2 * i + 1] : s4[2 * i];
        const float send = b1 ? s4[2 * i] : s4[2 * i + 1];
        s2[i] = keepv + __shfl_xor(send, 2);
      }
      const float keepv = b2 ? s2[1] : s2[0];
      const float send = b2 ? s2[0] : s2[1];
      const float v = keepv + __shfl_xor(send, 4) + lb[t & 7];
      const int g = batch[n];
      const int gidx = g - gfirst;
      const unsigned ev = enc_f32(v);
      if (gidx < 8)
        atomicMax(&smax[gidx][t & 7], ev);
      else
        atomicMax(&outmax[g * 8 + (t & 7)], ev);
    }
  }
  __syncthreads();
  if (t < 64) {
    const unsigned vv = smax[t >> 3][t & 7];
    if (vv) atomicMax(&outmax[(gfirst + (t >> 3)) * 8 + (t & 7)], vv);
  }
}

__global__ void combine_kernel(const unsigned* __restrict__ outmax,
                               float* __restrict__ out) {
  const int i = blockIdx.x * 64 + threadIdx.x;  // 8 x 64 = 512
  float s = 0.f;
#pragma unroll
  for (int l = 0; l < 4; ++l) s += dec_f32(outmax[l * GG * TT + i]);
  out[i] = s;
}

extern "C" void kernel_launch(void* const* d_in, const int* in_sizes, int n_in,
                              void* d_out, int out_size, void* d_ws,
                              size_t ws_size, hipStream_t stream) {
  const float* x      = (const float*)d_in[0];
  const int*   ei     = (const int*)d_in[1];
  const int*   batch  = (const int*)d_in[2];
  const float* fh_W1  = (const float*)d_in[3];
  const float* fh_b1  = (const float*)d_in[4];
  const float* fh_g1  = (const float*)d_in[5];
  const float* fh_be1 = (const float*)d_in[6];
  const float* fh_W2  = (const float*)d_in[7];
  const float* fh_b2  = (const float*)d_in[8];
  const float* fh_g2  = (const float*)d_in[9];
  const float* fh_be2 = (const float*)d_in[10];
  const float* cv_W1  = (const float*)d_in[11];
  const float* cv_b1  = (const float*)d_in[12];
  const float* cv_g1  = (const float*)d_in[13];
  const float* cv_be1 = (const float*)d_in[14];
  const float* cv_W2  = (const float*)d_in[15];
  const float* cv_b2  = (const float*)d_in[16];
  const float* cv_g2  = (const float*)d_in[17];
  const float* cv_be2 = (const float*)d_in[18];
  const float* lin_W  = (const float*)d_in[19];
  const float* lin_b  = (const float*)d_in[20];

  float* out = (float*)d_out;  // [64,8]
  float* h = out + GG * TT;    // [N,64] final h lives in d_out; running h buf.

  char* w = (char*)d_ws;
  float* stats = (float*)w;                       w += 128 * 4;
  float* ss = (float*)w;                          w += 128 * 4;
  unsigned* outmax = (unsigned*)w;                w += 4 * GG * TT * 4;
  int* bsum = (int*)w;                            w += 256 * 4;
  int* offs = (int*)w;                            w += (NN + 1) * 4;
  int* srcs = (int*)w;                            w += (size_t)EE * 4;
  w = (char*)(((size_t)w + 15) & ~(size_t)15);
  float* y1 = (float*)w;                          w += (size_t)NN * HH * 4;
  float* y2 = (float*)w;                          w += (size_t)NN * HH * 4;
  const size_t need_csr = (size_t)(w - (char*)d_ws);
  const bool use_csr = ws_size >= need_csr;
  float* agg = y2;             // aliased: agg dead before y2 written
  int* deg = (int*)y1;         // build-time aliases (dead before y1 written)
  int* cursor = ((int*)y1) + NN;

  hipMemsetAsync(stats, 0, 128 * sizeof(float), stream);
  hipMemsetAsync(outmax, 0, 4 * GG * TT * sizeof(unsigned), stream);

  if (use_csr) {
    hipMemsetAsync(deg, 0, NN * sizeof(int), stream);
    hist_kernel<<<(EE + 255) / 256, 256, 0, stream>>>(ei, deg);
    scan1_kernel<<<NB_SCAN, 256, 0, stream>>>(deg, bsum);
    scan2_kernel<<<1, 256, 0, stream>>>(bsum);
    scan3_kernel<<<NB_SCAN, 256, 0, stream>>>(deg, bsum, offs, cursor);
    fill_kernel<<<(EE + 255) / 256, 256, 0, stream>>>(ei, cursor, srcs);
  }

  // ---- first_h ----
  mm_kernel<FIN, 0><<<NN / 16, 256, 0, stream>>>(x, nullptr, nullptr, fh_W1, fh_b1, y1);
  stats_kernel<<<160, 256, 0, stream>>>(y1, stats);
  finalize_kernel<<<1, 64, 0, stream>>>(stats, fh_g1, fh_be1, ss);
  mm_kernel<HH, 1><<<NN / 16, 256, 0, stream>>>(y1, nullptr, ss, fh_W2, fh_b2, y2);
  stats_kernel<<<160, 256, 0, stream>>>(y2, stats);
  finalize_kernel<<<1, 64, 0, stream>>>(stats, fh_g2, fh_be2, ss);
  bnrelu_readout_kernel<<<(NN + RNODES - 1) / RNODES, 256, 0, stream>>>(
      y2, ss, h, lin_W, lin_b, batch, outmax);

  // ---- GIN conv layers ----
  for (int l = 0; l < NCONVS; ++l) {
    if (use_csr) {
      gather_kernel<<<(NN * 16) / 256, 256, 0, stream>>>(offs, srcs, h, agg);
    } else {
      hipMemsetAsync(agg, 0, (size_t)NN * HH * sizeof(float), stream);
      scatter_kernel<<<EE / 16, 256, 0, stream>>>(ei, h, agg);
    }
    mm_kernel<HH, 2><<<NN / 16, 256, 0, stream>>>(
        h, agg, nullptr, cv_W1 + l * HH * HH, cv_b1 + l * HH, y1);
    stats_kernel<<<160, 256, 0, stream>>>(y1, stats);
    finalize_kernel<<<1, 64, 0, stream>>>(stats, cv_g1 + l * HH, cv_be1 + l * HH, ss);
    mm_kernel<HH, 1><<<NN / 16, 256, 0, stream>>>(
        y1, nullptr, ss, cv_W2 + l * HH * HH, cv_b2 + l * HH, y2);
    stats_kernel<<<160, 256, 0, stream>>>(y2, stats);
    finalize_kernel<<<1, 64, 0, stream>>>(stats, cv_g2 + l * HH, cv_be2 + l * HH, ss);
    bnrelu_readout_kernel<<<(NN + RNODES - 1) / RNODES, 256, 0, stream>>>(
        y2, ss, h, lin_W + (l + 1) * HH * TT, lin_b + (l + 1) * TT, batch,
        outmax + (l + 1) * GG * TT);
  }
  combine_kernel<<<8, 64, 0, stream>>>(outmax, out);
}